// Round 7
// baseline (128.013 us; speedup 1.0000x reference)
//
#include <hip/hip_runtime.h>
#include <math.h>

#define B_SZ 2048
#define R_SZ 64
#define QB 8                     // q rows per kde block (band)
#define NB (B_SZ / QB)           // 256 bands = 256 kde blocks
#define IDX_MASK (B_SZ * R_SZ - 1)   // 0x1FFFF, power of 2

#define B_POW_NEG02 0.217637640824031f   // 2048^-0.2 = 2^-2.2
#define SQRT_2PI 2.5066282746310002f
#define LOG2E 1.44269504088896340736f

extern "C" __device__ float __ocml_native_exp2_f32(float);

typedef __attribute__((ext_vector_type(2))) float f32x2;

// ---------------------------------------------------------------------------
// ws layout (floats):
//   [0:64)    lscale        = 1/(B*h*sqrt(2pi))
//   [64:128)  cov_partial
//   [160]     ent_acc       (own line)
//   [192]     done2         (int, own line)
//   [256:256+131072)          U = kscale[r]*A   (prescaled, 512 KB)
//   [131328:131328+131072)    density (atomically accumulated, 512 KB)
// ---------------------------------------------------------------------------

// Kernel 1: stats + Gram row + cov row + U prescale + density/flag zeroing.
__global__ __launch_bounds__(1024) void cov_stats_kernel(const float* __restrict__ A,
                                                         float* __restrict__ U,
                                                         float* __restrict__ density,
                                                         float* __restrict__ lscale,
                                                         float* __restrict__ cov_partial,
                                                         float* __restrict__ ent_acc,
                                                         int* __restrict__ done2) {
    int i = blockIdx.x;
    int tid = threadIdx.x;
    int j = tid & 63, bg = tid >> 6;          // 16 b-groups

    float g = 0.f, sj = 0.f, s2j = 0.f;
#pragma unroll 4
    for (int b = bg; b < B_SZ; b += 16) {
        float ai = A[b * R_SZ + i];           // wave-uniform broadcast
        float aj = A[b * R_SZ + j];           // coalesced
        g = fmaf(ai, aj, g);
        sj += aj;
        s2j = fmaf(aj, aj, s2j);
    }

    __shared__ float gred[16][64], sred[16][64], s2red[16][64];
    __shared__ float gfin[64], sfin[64], hs[64];
    gred[bg][j] = g; sred[bg][j] = sj; s2red[bg][j] = s2j;
    __syncthreads();
    if (tid < 64) {
        float G = 0.f, S = 0.f, S2 = 0.f;
#pragma unroll
        for (int t = 0; t < 16; ++t) { G += gred[t][j]; S += sred[t][j]; S2 += s2red[t][j]; }
        gfin[j] = G;
        sfin[j] = S;
        float m = S * (1.f / (float)B_SZ);
        float var = (S2 - S * m) * (1.f / (float)(B_SZ - 1));   // ddof=1
        var = fmaxf(var, 0.f);
        float h = fmaxf(1.06f * sqrtf(var) * B_POW_NEG02, 1e-4f);
        hs[j] = sqrtf(0.5f * LOG2E) / h;      // exp2(-(k*d)^2) = exp(-0.5(d/h)^2)
        if (i == 0) lscale[j] = 1.0f / ((float)B_SZ * h * SQRT_2PI);
    }
    __syncthreads();
    if (tid < 64) {                            // covariance row i
        float m_j = sfin[j] * (1.f / (float)B_SZ);
        float m_i = sfin[i] * (1.f / (float)B_SZ);
        float cov = (gfin[j] - (float)B_SZ * m_i * m_j) * (1.f / (float)(B_SZ - 1));
        float v = (j == i) ? 0.f : cov * cov;
        for (int off = 32; off > 0; off >>= 1) v += __shfl_down(v, off, 64);
        if (j == 0) cov_partial[i] = v;
    }
    if (i == 0 && tid == 64) { *ent_acc = 0.f; *done2 = 0; }

    // prescale U rows + zero density (64 blocks x 2048 elems each, exact)
    int base = i * (32 * R_SZ);
    float k0 = hs[tid & 63];
    U[base + tid]        = A[base + tid]        * k0;
    U[base + 1024 + tid] = A[base + 1024 + tid] * k0;
    density[base + tid] = 0.f;
    density[base + 1024 + tid] = 0.f;
}

// ---------------------------------------------------------------------------
// Kernel 2: symmetric pairwise KDE. 256 blocks x 1024 thr.
// Block t: q-band [8t, 8t+8) (registers). Wave sg owns strip rows
// o = 8+64*sg .. +64 (bands d = 8sg+1..8sg+8, wrapped); each iter computes
// 8 exps (one per q), accumulating rows in registers AND the complete
// in-wave column sum -> one native-fadd atomic to density[s]. Antipodal
// band d=128 only for t<128 (wave 15). Intra 8x8 band: wave 0, rows only.
// 2-deep register prefetch hides L2 latency. LDS-reduce rows at end.
// ---------------------------------------------------------------------------
__global__ __launch_bounds__(1024) void kde_sym_kernel(const float* __restrict__ U,
                                                       float* __restrict__ density) {
    int tid = threadIdx.x;
    int r = tid & 63, sg = tid >> 6;
    int t = blockIdx.x;
    int q0 = t * QB;

    f32x2 uq01 = { U[(q0 + 0) * R_SZ + r], U[(q0 + 1) * R_SZ + r] };
    f32x2 uq23 = { U[(q0 + 2) * R_SZ + r], U[(q0 + 3) * R_SZ + r] };
    f32x2 uq45 = { U[(q0 + 4) * R_SZ + r], U[(q0 + 5) * R_SZ + r] };
    f32x2 uq67 = { U[(q0 + 6) * R_SZ + r], U[(q0 + 7) * R_SZ + r] };
    f32x2 r01 = {0.f,0.f}, r23 = {0.f,0.f}, r45 = {0.f,0.f}, r67 = {0.f,0.f};

    // ---- wave 0: intra-band 8x8 (rows only, no col credit) ----
    if (sg == 0) {
#pragma unroll
        for (int i = 0; i < QB; ++i) {
            float us = U[(q0 + i) * R_SZ + r];      // L1-hot (just loaded above)
            f32x2 uss = { us, us };
            f32x2 d01 = uq01 - uss, d23 = uq23 - uss;
            f32x2 d45 = uq45 - uss, d67 = uq67 - uss;
            f32x2 n01 = -d01*d01, n23 = -d23*d23, n45 = -d45*d45, n67 = -d67*d67;
            f32x2 e01 = { __ocml_native_exp2_f32(n01.x), __ocml_native_exp2_f32(n01.y) };
            f32x2 e23 = { __ocml_native_exp2_f32(n23.x), __ocml_native_exp2_f32(n23.y) };
            f32x2 e45 = { __ocml_native_exp2_f32(n45.x), __ocml_native_exp2_f32(n45.y) };
            f32x2 e67 = { __ocml_native_exp2_f32(n67.x), __ocml_native_exp2_f32(n67.y) };
            r01 += e01; r23 += e23; r45 += e45; r67 += e67;
        }
    }

    // ---- main strip: 64 iters (56 for wave 15 of blocks t>=128) ----
    int niter = (sg == 15 && t >= NB / 2) ? 56 : 64;
    int row0 = (q0 + 8 + 64 * sg) & (B_SZ - 1);
    int idx0 = row0 * R_SZ + r;
    int li = idx0;                         // load (prefetch) index
    float p0 = U[li]; li = (li + R_SZ) & IDX_MASK;
    float p1 = U[li]; li = (li + R_SZ) & IDX_MASK;
    int ui = idx0;                         // use/atomic index
    for (int i = 0; i < niter; ++i) {
        float us = p0; p0 = p1;
        p1 = U[li];                        // prefetch i+2 (mask keeps in-bounds)
        li = (li + R_SZ) & IDX_MASK;
        f32x2 uss = { us, us };
        f32x2 d01 = uq01 - uss, d23 = uq23 - uss;
        f32x2 d45 = uq45 - uss, d67 = uq67 - uss;
        f32x2 n01 = -d01*d01, n23 = -d23*d23, n45 = -d45*d45, n67 = -d67*d67;
        f32x2 e01 = { __ocml_native_exp2_f32(n01.x), __ocml_native_exp2_f32(n01.y) };
        f32x2 e23 = { __ocml_native_exp2_f32(n23.x), __ocml_native_exp2_f32(n23.y) };
        f32x2 e45 = { __ocml_native_exp2_f32(n45.x), __ocml_native_exp2_f32(n45.y) };
        f32x2 e67 = { __ocml_native_exp2_f32(n67.x), __ocml_native_exp2_f32(n67.y) };
        r01 += e01; r23 += e23; r45 += e45; r67 += e67;
        f32x2 t0 = e01 + e23, t1 = e45 + e67;
        f32x2 t2 = t0 + t1;
        unsafeAtomicAdd(&density[ui], t2.x + t2.y);   // native global_atomic_add_f32
        ui = (ui + R_SZ) & IDX_MASK;
    }

    // ---- cross-wave reduce of the 8 q-row sums -> atomic add to density ----
    __shared__ float red[16][QB][64];
    red[sg][0][r] = r01.x; red[sg][1][r] = r01.y;
    red[sg][2][r] = r23.x; red[sg][3][r] = r23.y;
    red[sg][4][r] = r45.x; red[sg][5][r] = r45.y;
    red[sg][6][r] = r67.x; red[sg][7][r] = r67.y;
    __syncthreads();
    if (sg < QB) {                          // wave sg owns q-row q0+sg
        float S = 0.f;
#pragma unroll
        for (int w = 0; w < 16; ++w) S += red[w][sg][r];
        unsafeAtomicAdd(&density[(q0 + sg) * R_SZ + r], S);
    }
}

// ---------------------------------------------------------------------------
// Kernel 3: entropy over assembled density + grid-final fold.
// 64 blocks x 1024; 2 elems/thread; last block folds cov+ent -> out[0].
// ---------------------------------------------------------------------------
__global__ __launch_bounds__(1024) void entropy_kernel(const float* __restrict__ density,
                                                       const float* __restrict__ lscale,
                                                       const float* __restrict__ cov_partial,
                                                       float* __restrict__ ent_acc,
                                                       int* __restrict__ done2,
                                                       float* __restrict__ out) {
    int tid = threadIdx.x;
    int r = tid & 63, sg = tid >> 6;
    float ls = lscale[r];
    int f = blockIdx.x * 2048 + tid;
    float v = __logf(fmaf(density[f], ls, 1e-8f))
            + __logf(fmaf(density[f + 1024], ls, 1e-8f));
    for (int off = 32; off > 0; off >>= 1) v += __shfl_down(v, off, 64);
    __shared__ float wr[16];
    if (r == 0) wr[sg] = v;
    __syncthreads();
    __shared__ int lastflag;
    if (tid == 0) {
        float s = 0.f;
#pragma unroll
        for (int w = 0; w < 16; ++w) s += wr[w];
        atomicAdd(ent_acc, s);             // once per block
        __threadfence();
        int prev = atomicAdd(done2, 1);
        lastflag = (prev == 63);
    }
    __syncthreads();
    if (lastflag && tid < 64) {            // grid-final fold in last block
        __threadfence();
        float v2 = cov_partial[tid];
        for (int off = 32; off > 0; off >>= 1) v2 += __shfl_down(v2, off, 64);
        if (tid == 0) {
            float ent = __hip_atomic_load(ent_acc, __ATOMIC_ACQUIRE,
                                          __HIP_MEMORY_SCOPE_AGENT);
            out[0] = ent * (1.0f / ((float)B_SZ * (float)R_SZ)) + v2;
        }
    }
}

extern "C" void kernel_launch(void* const* d_in, const int* in_sizes, int n_in,
                              void* d_out, int out_size, void* d_ws, size_t ws_size,
                              hipStream_t stream) {
    const float* A = (const float*)d_in[0];
    float* out = (float*)d_out;

    float* wsf = (float*)d_ws;
    float* lscale      = wsf;                 // 64
    float* cov_partial = wsf + 64;            // 64
    float* ent_acc     = wsf + 160;           // isolated line
    int*   done2       = (int*)(wsf + 192);
    float* U           = wsf + 256;           // 2048*64
    float* density     = wsf + 256 + B_SZ * R_SZ;

    cov_stats_kernel<<<R_SZ, 1024, 0, stream>>>(A, U, density, lscale, cov_partial,
                                                ent_acc, done2);
    kde_sym_kernel<<<NB, 1024, 0, stream>>>(U, density);
    entropy_kernel<<<64, 1024, 0, stream>>>(density, lscale, cov_partial,
                                            ent_acc, done2, out);
}